// Round 9
// baseline (305.992 us; speedup 1.0000x reference)
//
#include <hip/hip_runtime.h>
#include <math.h>

#define E_TOT   160000
#define BE      64                   // edges per block
#define TPB     256                  // 4 waves; wave p owns j = 4p..4p+3
#define NBLK    (E_TOT / BE)         // 2500
#define TV_OFF  16384                // tv f32 [16][64]
#define T2S     52                   // tmp2 row stride (floats)
#define SMEM_SZ 20480                // h hi 8K | h lo 8K | tv 4K ; tmp2 13.3K overlays h

typedef __attribute__((ext_vector_type(8))) __bf16 bf16x8;
typedef __attribute__((ext_vector_type(4))) float f32x4;

static __device__ __forceinline__ unsigned short f2bf(float v) {
    unsigned int u = __float_as_uint(v);
    u += 0x7FFFu + ((u >> 16) & 1u);
    return (unsigned short)(u >> 16);
}
static __device__ __forceinline__ float bf2f(unsigned int s) {
    return __uint_as_float(s << 16);
}

// exact-enough GELU: Abramowitz-Stegun 7.1.26 erf (|err| < ~1e-6)
static __device__ __forceinline__ float gelu_exact(float a) {
    float x = a * 0.70710678118654752f;
    float s = fabsf(x);
    float t = __builtin_amdgcn_rcpf(fmaf(0.3275911f, s, 1.0f));
    float p = fmaf(1.061405429f, t, -1.453152027f);
    p = fmaf(p, t, 1.421413741f);
    p = fmaf(p, t, -0.284496736f);
    p = fmaf(p, t, 0.254829592f);
    p = p * t;
    float er = fmaf(-p, __expf(-s * s), 1.0f);
    er = copysignf(er, x);
    return 0.5f * a * (1.0f + er);
}

// ---- pre-kernel: split W2 into bf16 hi/lo fragment chunks; bias-B chunks ----
__global__ __launch_bounds__(256) void w_split(
    const float* __restrict__ W2, const float* __restrict__ b2l,
    uint4* __restrict__ hi4, uint4* __restrict__ lo4, uint4* __restrict__ bb4)
{
    const int c = blockIdx.x * 256 + threadIdx.x;
    if (c < 6144) {
        const int lane = c & 63, rest = c >> 6;
        const int kk   = rest & 1, tj = rest >> 1;
        const int j    = tj & 15,  t  = tj >> 4;
        const int grp  = lane >> 4, r16 = lane & 15;
        const float* src = W2 + (size_t)((t * 16 + r16) * 16 + j) * 64 + kk * 32 + grp * 8;
        union { uint4 u; unsigned short s[8]; } H, L;
        #pragma unroll
        for (int i = 0; i < 8; ++i) {
            float w = src[i];
            unsigned short h = f2bf(w);
            H.s[i] = h;
            L.s[i] = f2bf(w - bf2f(h));
        }
        hi4[c] = H.u;
        lo4[c] = L.u;
    } else if (c < 6144 + 192) {
        const int cc   = c - 6144;
        const int lane = cc & 63, t = cc >> 6;
        const int grp  = lane >> 4, r16 = lane & 15;
        union { uint4 u; unsigned short s[8]; } B;
        #pragma unroll
        for (int i = 0; i < 8; ++i)
            B.s[i] = (grp < 2) ? f2bf(b2l[(t * 16 + r16) * 16 + grp * 8 + i])
                               : (unsigned short)0;
        bb4[cc] = B.u;
    }
}

// reduction helpers: acc slot index is ALWAYS a literal at expansion site
#define RED_STORE(S)                                                \
    {                                                               \
        _Pragma("unroll")                                           \
        for (int t = 0; t < 3; ++t) {                               \
            t2p[(eb + 0) * T2S + t * 16 + r16] = acc[S][t].x;       \
            t2p[(eb + 1) * T2S + t * 16 + r16] = acc[S][t].y;       \
            t2p[(eb + 2) * T2S + t * 16 + r16] = acc[S][t].z;       \
            t2p[(eb + 3) * T2S + t * 16 + r16] = acc[S][t].w;       \
        }                                                           \
    }
#define RED_ADD(S)                                                  \
    {                                                               \
        _Pragma("unroll")                                           \
        for (int t = 0; t < 3; ++t) {                               \
            t2p[(eb + 0) * T2S + t * 16 + r16] += acc[S][t].x;      \
            t2p[(eb + 1) * T2S + t * 16 + r16] += acc[S][t].y;      \
            t2p[(eb + 2) * T2S + t * 16 + r16] += acc[S][t].z;      \
            t2p[(eb + 3) * T2S + t * 16 + r16] += acc[S][t].w;      \
        }                                                           \
    }

// ---- main kernel: 256 threads = 4 waves; wave p owns j=4p..4p+3, all tiles ----
__global__ __launch_bounds__(TPB, 4) void eq_attn_kernel(
    const float* __restrict__ b1,    // (E, 4, 2)
    const float* __restrict__ b2,    // (E, 2, 4)
    const float* __restrict__ ef,    // (E, 32)
    const float* __restrict__ f,     // (N, 8, 4)
    const int*   __restrict__ nidx,  // (E)
    const float* __restrict__ W1,    // (64, 32)
    const float* __restrict__ b1l,   // (64)
    const float* __restrict__ Wout,  // (16, 8)
    const float* __restrict__ bias,  // (8)
    const uint4* __restrict__ wsh,   // W2 hi chunks (6144)
    const uint4* __restrict__ wsl,   // W2 lo chunks (6144)
    const uint4* __restrict__ bb,    // bias-B chunks (192)
    float* __restrict__ out)         // (N, 8, 4)
{
    __shared__ unsigned char smem[SMEM_SZ];
    const int tid = threadIdx.x;
    const int p   = tid >> 6;        // wave index 0..3
    const int el  = tid & 63;        // lane = edge within block (phase A)
    const int r16 = el & 15;
    const int grp = el >> 4;
    const int e0  = blockIdx.x * BE;
    const int e   = e0 + el;

    // ================= phase A =================
    // layer 1: wave p computes hid in [p*16, p*16+16) for edge el
    {
        float efr[32];
        const float4* ef4 = reinterpret_cast<const float4*>(ef + (size_t)e * 32);
        #pragma unroll
        for (int i = 0; i < 8; ++i) {
            float4 v = ef4[i];
            efr[i*4+0] = v.x; efr[i*4+1] = v.y; efr[i*4+2] = v.z; efr[i*4+3] = v.w;
        }
        #pragma unroll
        for (int cc = 0; cc < 2; ++cc) {
            const int c8 = 2 * p + cc;
            union { uint4 u; unsigned short s[8]; } H, L;
            #pragma unroll
            for (int i = 0; i < 8; ++i) {
                const int hid = c8 * 8 + i;
                float acc1 = b1l[hid];
                #pragma unroll
                for (int c = 0; c < 32; ++c)
                    acc1 = fmaf(efr[c], W1[hid * 32 + c], acc1);
                float v = gelu_exact(acc1);
                unsigned short hs = f2bf(v);
                H.s[i] = hs;
                L.s[i] = f2bf(v - bf2f(hs));
            }
            const int ch = c8 ^ (el & 7);
            *(uint4*)(smem +        el * 128 + ch * 16) = H.u;
            *(uint4*)(smem + 8192 + el * 128 + ch * 16) = L.u;
        }
    }
    // tmpv split across waves: wave p computes m = 2p, 2p+1 (rows j = 4p..4p+3)
    {
        const int src = nidx[e];
        float b1r[8];
        const float4* b14 = reinterpret_cast<const float4*>(b1 + (size_t)e * 8);
        float4 u0 = b14[0], u1 = b14[1];
        b1r[0]=u0.x; b1r[1]=u0.y; b1r[2]=u0.z; b1r[3]=u0.w;
        b1r[4]=u1.x; b1r[5]=u1.y; b1r[6]=u1.z; b1r[7]=u1.w;
        float* tvp = (float*)(smem + TV_OFF);
        const float4* f4 = reinterpret_cast<const float4*>(f + (size_t)src * 32);
        #pragma unroll
        for (int mm = 0; mm < 2; ++mm) {
            const int m = 2 * p + mm;
            float4 v = f4[m];
            float a0 = v.x * b1r[0] + v.y * b1r[2] + v.z * b1r[4] + v.w * b1r[6];
            float a1 = v.x * b1r[1] + v.y * b1r[3] + v.z * b1r[5] + v.w * b1r[7];
            tvp[(m*2+0) * 64 + el] = a0;
            tvp[(m*2+1) * 64 + el] = a1;
        }
    }

    __syncthreads();

    // ===== acc[slot][t]; slot s holds tile (p+s)&3 =====
    // bias-GEMM init on wave 0 only (its slots are tiles 0..3 directly)
    f32x4 acc[4][3];
    if (p == 0) {
        const float* tvp = (const float*)(smem + TV_OFF);
        bf16x8 blb[3];
        #pragma unroll
        for (int t = 0; t < 3; ++t) {
            uint4 u = bb[t * 64 + el];
            blb[t] = *(bf16x8*)&u;
        }
        #pragma unroll
        for (int s = 0; s < 4; ++s) {
            union { uint4 u; unsigned short sh[8]; } P;
            #pragma unroll
            for (int i = 0; i < 8; ++i) {
                float v = (grp < 2) ? tvp[(grp * 8 + i) * 64 + s * 16 + r16] : 0.0f;
                P.sh[i] = f2bf(v);
            }
            bf16x8 tvb = *(bf16x8*)&P.u;
            #pragma unroll
            for (int t = 0; t < 3; ++t)
                acc[s][t] = __builtin_amdgcn_mfma_f32_16x16x32_bf16(
                    tvb, blb[t], (f32x4){0.f, 0.f, 0.f, 0.f}, 0, 0, 0);
        }
    } else {
        #pragma unroll
        for (int s = 0; s < 4; ++s)
            #pragma unroll
            for (int t = 0; t < 3; ++t)
                acc[s][t] = (f32x4){0.f, 0.f, 0.f, 0.f};
    }

    // ========== phase B : own 4 j, ALL 4 tiles (slot-static acc) ==========
    const float4* tv4 = (const float4*)(smem + TV_OFF);
    #pragma unroll
    for (int jj = 0; jj < 4; ++jj) {
        const int j = p * 4 + jj;
        bf16x8 Bhi[3][2], Blo[3][2];
        #pragma unroll
        for (int t = 0; t < 3; ++t)
            #pragma unroll
            for (int kk = 0; kk < 2; ++kk) {
                const int chunk = ((t * 16 + j) * 2 + kk) * 64 + el;
                Bhi[t][kk] = ((const bf16x8*)wsh)[chunk];
                Blo[t][kk] = ((const bf16x8*)wsl)[chunk];
            }
        #pragma unroll
        for (int s = 0; s < 4; ++s) {
            const int mt  = (p + s) & 3;            // runtime: addresses only
            const int row = mt * 16 + r16;
            const int ch0 = grp ^ (r16 & 7);
            const int ch1 = (4 + grp) ^ (r16 & 7);
            bf16x8 Ah0 = *(const bf16x8*)(smem +        row * 128 + ch0 * 16);
            bf16x8 Ah1 = *(const bf16x8*)(smem +        row * 128 + ch1 * 16);
            bf16x8 Al0 = *(const bf16x8*)(smem + 8192 + row * 128 + ch0 * 16);
            bf16x8 Al1 = *(const bf16x8*)(smem + 8192 + row * 128 + ch1 * 16);
            float4 tv = tv4[j * 16 + mt * 4 + grp];
            #pragma unroll
            for (int t = 0; t < 3; ++t) {
                f32x4 rw = (f32x4){0.f, 0.f, 0.f, 0.f};
                rw = __builtin_amdgcn_mfma_f32_16x16x32_bf16(Ah0, Bhi[t][0], rw, 0, 0, 0);
                rw = __builtin_amdgcn_mfma_f32_16x16x32_bf16(Ah1, Bhi[t][1], rw, 0, 0, 0);
                rw = __builtin_amdgcn_mfma_f32_16x16x32_bf16(Al0, Bhi[t][0], rw, 0, 0, 0);
                rw = __builtin_amdgcn_mfma_f32_16x16x32_bf16(Al1, Bhi[t][1], rw, 0, 0, 0);
                rw = __builtin_amdgcn_mfma_f32_16x16x32_bf16(Ah0, Blo[t][0], rw, 0, 0, 0);
                rw = __builtin_amdgcn_mfma_f32_16x16x32_bf16(Ah1, Blo[t][1], rw, 0, 0, 0);
                acc[s][t].x = fmaf(tv.x, rw.x, acc[s][t].x);
                acc[s][t].y = fmaf(tv.y, rw.y, acc[s][t].y);
                acc[s][t].z = fmaf(tv.z, rw.z, acc[s][t].z);
                acc[s][t].w = fmaf(tv.w, rw.w, acc[s][t].w);
            }
        }
    }

    __syncthreads();   // all h/tv reads done before tmp2 overlays h

    // ===== cross-wave reduction: 4 hand-written rounds, acc index literal =====
    {
        float* t2p = (float*)smem;
        {   // round 0: store slot 0 -> tile p
            const int eb = p * 16 + grp * 4;
            RED_STORE(0);
        }
        __syncthreads();
        {   // round 1: add slot 1 -> tile (p+1)&3
            const int eb = (((p + 1) & 3) * 16) + grp * 4;
            RED_ADD(1);
        }
        __syncthreads();
        {   // round 2: add slot 2 -> tile (p+2)&3
            const int eb = (((p + 2) & 3) * 16) + grp * 4;
            RED_ADD(2);
        }
        __syncthreads();
        {   // round 3: add slot 3 -> tile (p+3)&3
            const int eb = (((p + 3) & 3) * 16) + grp * 4;
            RED_ADD(3);
        }
        __syncthreads();
    }

    // ================= phase C : wave p, lanes 0..15 -> node e0/16 + p =================
    if (el < 16) {
        const int erow = p * 16 + el;          // edge within block
        const int ec   = e0 + erow;            // global edge
        float t2[48];
        {
            const float* t2r = (const float*)smem + (size_t)erow * T2S;
            #pragma unroll
            for (int o2 = 0; o2 < 48; ++o2) t2[o2] = t2r[o2];
        }
        float b2r[8];
        {
            const float4* b24 = reinterpret_cast<const float4*>(b2 + (size_t)ec * 8);
            float4 u0 = b24[0], u1 = b24[1];
            b2r[0]=u0.x; b2r[1]=u0.y; b2r[2]=u0.z; b2r[3]=u0.w;
            b2r[4]=u1.x; b2r[5]=u1.y; b2r[6]=u1.z; b2r[7]=u1.w;
        }
        float q[8][4];
        #pragma unroll
        for (int o = 0; o < 8; ++o) {
            float t0 = t2[2*o+0], t1 = t2[2*o+1];
            #pragma unroll
            for (int d = 0; d < 4; ++d)
                q[o][d] = fmaf(t0, b2r[d], t1 * b2r[4+d]);
        }
        float scores[4] = {0.f, 0.f, 0.f, 0.f};
        #pragma unroll
        for (int o = 0; o < 8; ++o) {
            float t0 = t2[16+2*o+0], t1 = t2[16+2*o+1];
            float sacc = 0.f;
            #pragma unroll
            for (int d = 0; d < 4; ++d) {
                float kr = fmaf(t0, b2r[d], t1 * b2r[4+d]);
                sacc = fmaf(q[o][d], kr, sacc);
            }
            scores[o >> 1] += sacc;
        }
        float vv[8][4];
        #pragma unroll
        for (int o = 0; o < 8; ++o) {
            float t0 = t2[32+2*o+0], t1 = t2[32+2*o+1];
            #pragma unroll
            for (int d = 0; d < 4; ++d)
                vv[o][d] = fmaf(t0, b2r[d], t1 * b2r[4+d]);
        }
        // softmax over the 16 neighbor lanes
        float attn[4];
        #pragma unroll
        for (int hh = 0; hh < 4; ++hh) {
            float s = scores[hh] * 0.35355339059327373f;
            float mx = s;
            #pragma unroll
            for (int msk = 8; msk; msk >>= 1)
                mx = fmaxf(mx, __shfl_xor(mx, msk, 16));
            float pr = __expf(s - mx);
            float ps = pr;
            #pragma unroll
            for (int msk = 8; msk; msk >>= 1)
                ps += __shfl_xor(ps, msk, 16);
            attn[hh] = pr / ps;
        }
        float osum[8][4];
        #pragma unroll
        for (int m = 0; m < 8; ++m) {
            float w = attn[m >> 1];
            #pragma unroll
            for (int d = 0; d < 4; ++d) {
                float val = w * vv[m][d];
                #pragma unroll
                for (int msk = 8; msk; msk >>= 1)
                    val += __shfl_xor(val, msk, 16);
                osum[m][d] = val;
            }
        }
        if (el == 0) {
            const int n = ec >> 4;
            #pragma unroll
            for (int od = 0; od < 8; ++od) {
                #pragma unroll
                for (int d = 0; d < 4; ++d) {
                    const int row = (d == 0) ? od : (8 + od);
                    float a = (d == 0) ? bias[od] : 0.f;
                    #pragma unroll
                    for (int m = 0; m < 8; ++m)
                        a = fmaf(Wout[row * 8 + m], osum[m][d], a);
                    out[(size_t)n * 32 + od * 4 + d] = a;
                }
            }
        }
    }
}

extern "C" void kernel_launch(void* const* d_in, const int* in_sizes, int n_in,
                              void* d_out, int out_size, void* d_ws, size_t ws_size,
                              hipStream_t stream) {
    const float* b1   = (const float*)d_in[0];
    const float* b2   = (const float*)d_in[1];
    const float* ef   = (const float*)d_in[2];
    const float* f    = (const float*)d_in[3];
    const int*   nidx = (const int*)d_in[4];
    const float* W1   = (const float*)d_in[5];
    const float* b1l  = (const float*)d_in[6];
    const float* W2   = (const float*)d_in[7];
    const float* b2l  = (const float*)d_in[8];
    const float* Wout = (const float*)d_in[9];
    const float* bias = (const float*)d_in[10];
    float* out = (float*)d_out;

    uint4* wsh = (uint4*)d_ws;              // 6144 chunks
    uint4* wsl = wsh + 6144;                // 6144 chunks
    uint4* bb  = wsh + 12288;               // 192 chunks

    hipLaunchKernelGGL(w_split, dim3(25), dim3(256), 0, stream, W2, b2l, wsh, wsl, bb);
    hipLaunchKernelGGL(eq_attn_kernel, dim3(NBLK), dim3(TPB), 0, stream,
                       b1, b2, ef, f, nidx, W1, b1l, Wout, bias,
                       (const uint4*)wsh, (const uint4*)wsl, (const uint4*)bb, out);
}

// Round 10
// 181.640 us; speedup vs baseline: 1.6846x; 1.6846x over previous
//
#include <hip/hip_runtime.h>
#include <math.h>

#define E_TOT   160000
#define BE      64                   // edges per block
#define TPB     256                  // 4 waves; wave p owns j = 4p..4p+3
#define NBLK    (E_TOT / BE)         // 2500
#define TV_OFF  16384                // tv f32 [16][64]
#define T2S     52                   // tmp2 row stride (floats)
#define SMEM_SZ 20480                // h hi 8K | h lo 8K | tv 4K ; tmp2 13.3K overlays h

typedef __attribute__((ext_vector_type(8))) __bf16 bf16x8;
typedef __attribute__((ext_vector_type(4))) float f32x4;

static __device__ __forceinline__ unsigned short f2bf(float v) {
    unsigned int u = __float_as_uint(v);
    u += 0x7FFFu + ((u >> 16) & 1u);
    return (unsigned short)(u >> 16);
}
static __device__ __forceinline__ float bf2f(unsigned int s) {
    return __uint_as_float(s << 16);
}

// exact-enough GELU: Abramowitz-Stegun 7.1.26 erf (|err| < ~1e-6)
static __device__ __forceinline__ float gelu_exact(float a) {
    float x = a * 0.70710678118654752f;
    float s = fabsf(x);
    float t = __builtin_amdgcn_rcpf(fmaf(0.3275911f, s, 1.0f));
    float p = fmaf(1.061405429f, t, -1.453152027f);
    p = fmaf(p, t, 1.421413741f);
    p = fmaf(p, t, -0.284496736f);
    p = fmaf(p, t, 0.254829592f);
    p = p * t;
    float er = fmaf(-p, __expf(-s * s), 1.0f);
    er = copysignf(er, x);
    return 0.5f * a * (1.0f + er);
}

// ---- pre-kernel: split W2 into bf16 hi/lo fragment chunks; bias-B chunks ----
__global__ __launch_bounds__(256) void w_split(
    const float* __restrict__ W2, const float* __restrict__ b2l,
    uint4* __restrict__ hi4, uint4* __restrict__ lo4, uint4* __restrict__ bb4)
{
    const int c = blockIdx.x * 256 + threadIdx.x;
    if (c < 6144) {
        const int lane = c & 63, rest = c >> 6;
        const int kk   = rest & 1, tj = rest >> 1;
        const int j    = tj & 15,  t  = tj >> 4;
        const int grp  = lane >> 4, r16 = lane & 15;
        const float* src = W2 + (size_t)((t * 16 + r16) * 16 + j) * 64 + kk * 32 + grp * 8;
        union { uint4 u; unsigned short s[8]; } H, L;
        #pragma unroll
        for (int i = 0; i < 8; ++i) {
            float w = src[i];
            unsigned short h = f2bf(w);
            H.s[i] = h;
            L.s[i] = f2bf(w - bf2f(h));
        }
        hi4[c] = H.u;
        lo4[c] = L.u;
    } else if (c < 6144 + 192) {
        const int cc   = c - 6144;
        const int lane = cc & 63, t = cc >> 6;
        const int grp  = lane >> 4, r16 = lane & 15;
        union { uint4 u; unsigned short s[8]; } B;
        #pragma unroll
        for (int i = 0; i < 8; ++i)
            B.s[i] = (grp < 2) ? f2bf(b2l[(t * 16 + r16) * 16 + grp * 8 + i])
                               : (unsigned short)0;
        bb4[cc] = B.u;
    }
}

// reduction helpers: acc slot index is ALWAYS a literal at expansion site
#define RED_STORE(S)                                                \
    {                                                               \
        _Pragma("unroll")                                           \
        for (int t = 0; t < 3; ++t) {                               \
            t2p[(eb + 0) * T2S + t * 16 + r16] = acc[S][t].x;       \
            t2p[(eb + 1) * T2S + t * 16 + r16] = acc[S][t].y;       \
            t2p[(eb + 2) * T2S + t * 16 + r16] = acc[S][t].z;       \
            t2p[(eb + 3) * T2S + t * 16 + r16] = acc[S][t].w;       \
        }                                                           \
    }
#define RED_ADD(S)                                                  \
    {                                                               \
        _Pragma("unroll")                                           \
        for (int t = 0; t < 3; ++t) {                               \
            t2p[(eb + 0) * T2S + t * 16 + r16] += acc[S][t].x;      \
            t2p[(eb + 1) * T2S + t * 16 + r16] += acc[S][t].y;      \
            t2p[(eb + 2) * T2S + t * 16 + r16] += acc[S][t].z;      \
            t2p[(eb + 3) * T2S + t * 16 + r16] += acc[S][t].w;      \
        }                                                           \
    }

// ---- main kernel: 256 threads = 4 waves; wave p owns j=4p..4p+3, all tiles ----
__global__ __launch_bounds__(TPB, 2) void eq_attn_kernel(
    const float* __restrict__ b1,    // (E, 4, 2)
    const float* __restrict__ b2,    // (E, 2, 4)
    const float* __restrict__ ef,    // (E, 32)
    const float* __restrict__ f,     // (N, 8, 4)
    const int*   __restrict__ nidx,  // (E)
    const float* __restrict__ W1,    // (64, 32)
    const float* __restrict__ b1l,   // (64)
    const float* __restrict__ Wout,  // (16, 8)
    const float* __restrict__ bias,  // (8)
    const uint4* __restrict__ wsh,   // W2 hi chunks (6144)
    const uint4* __restrict__ wsl,   // W2 lo chunks (6144)
    const uint4* __restrict__ bb,    // bias-B chunks (192)
    float* __restrict__ out)         // (N, 8, 4)
{
    __shared__ unsigned char smem[SMEM_SZ];
    const int tid = threadIdx.x;
    const int p   = tid >> 6;        // wave index 0..3
    const int el  = tid & 63;        // lane = edge within block (phase A)
    const int r16 = el & 15;
    const int grp = el >> 4;
    const int e0  = blockIdx.x * BE;
    const int e   = e0 + el;

    // ================= phase A =================
    // layer 1: wave p computes hid in [p*16, p*16+16) for edge el
    {
        float efr[32];
        const float4* ef4 = reinterpret_cast<const float4*>(ef + (size_t)e * 32);
        #pragma unroll
        for (int i = 0; i < 8; ++i) {
            float4 v = ef4[i];
            efr[i*4+0] = v.x; efr[i*4+1] = v.y; efr[i*4+2] = v.z; efr[i*4+3] = v.w;
        }
        #pragma unroll
        for (int cc = 0; cc < 2; ++cc) {
            const int c8 = 2 * p + cc;
            union { uint4 u; unsigned short s[8]; } H, L;
            #pragma unroll
            for (int i = 0; i < 8; ++i) {
                const int hid = c8 * 8 + i;
                float acc1 = b1l[hid];
                #pragma unroll
                for (int c = 0; c < 32; ++c)
                    acc1 = fmaf(efr[c], W1[hid * 32 + c], acc1);
                float v = gelu_exact(acc1);
                unsigned short hs = f2bf(v);
                H.s[i] = hs;
                L.s[i] = f2bf(v - bf2f(hs));
            }
            const int ch = c8 ^ (el & 7);
            *(uint4*)(smem +        el * 128 + ch * 16) = H.u;
            *(uint4*)(smem + 8192 + el * 128 + ch * 16) = L.u;
        }
    }
    // tmpv split across waves: wave p computes m = 2p, 2p+1
    {
        const int src = nidx[e];
        float b1r[8];
        const float4* b14 = reinterpret_cast<const float4*>(b1 + (size_t)e * 8);
        float4 u0 = b14[0], u1 = b14[1];
        b1r[0]=u0.x; b1r[1]=u0.y; b1r[2]=u0.z; b1r[3]=u0.w;
        b1r[4]=u1.x; b1r[5]=u1.y; b1r[6]=u1.z; b1r[7]=u1.w;
        float* tvp = (float*)(smem + TV_OFF);
        const float4* f4 = reinterpret_cast<const float4*>(f + (size_t)src * 32);
        #pragma unroll
        for (int mm = 0; mm < 2; ++mm) {
            const int m = 2 * p + mm;
            float4 v = f4[m];
            float a0 = v.x * b1r[0] + v.y * b1r[2] + v.z * b1r[4] + v.w * b1r[6];
            float a1 = v.x * b1r[1] + v.y * b1r[3] + v.z * b1r[5] + v.w * b1r[7];
            tvp[(m*2+0) * 64 + el] = a0;
            tvp[(m*2+1) * 64 + el] = a1;
        }
    }

    __syncthreads();

    // ===== acc[slot][t]; slot s holds tile (p+s)&3 =====
    // bias-GEMM init on wave 0 only (its slots are tiles 0..3 directly)
    f32x4 acc[4][3];
    if (p == 0) {
        const float* tvp = (const float*)(smem + TV_OFF);
        bf16x8 blb[3];
        #pragma unroll
        for (int t = 0; t < 3; ++t) {
            uint4 u = bb[t * 64 + el];
            blb[t] = *(bf16x8*)&u;
        }
        #pragma unroll
        for (int s = 0; s < 4; ++s) {
            union { uint4 u; unsigned short sh[8]; } P;
            #pragma unroll
            for (int i = 0; i < 8; ++i) {
                float v = (grp < 2) ? tvp[(grp * 8 + i) * 64 + s * 16 + r16] : 0.0f;
                P.sh[i] = f2bf(v);
            }
            bf16x8 tvb = *(bf16x8*)&P.u;
            #pragma unroll
            for (int t = 0; t < 3; ++t)
                acc[s][t] = __builtin_amdgcn_mfma_f32_16x16x32_bf16(
                    tvb, blb[t], (f32x4){0.f, 0.f, 0.f, 0.f}, 0, 0, 0);
        }
    } else {
        #pragma unroll
        for (int s = 0; s < 4; ++s)
            #pragma unroll
            for (int t = 0; t < 3; ++t)
                acc[s][t] = (f32x4){0.f, 0.f, 0.f, 0.f};
    }

    // ========== phase B : own 4 j, ALL 4 tiles (slot-static acc) ==========
    const float4* tv4 = (const float4*)(smem + TV_OFF);
    #pragma unroll
    for (int jj = 0; jj < 4; ++jj) {
        const int j = p * 4 + jj;
        bf16x8 Bhi[3][2], Blo[3][2];
        #pragma unroll
        for (int t = 0; t < 3; ++t)
            #pragma unroll
            for (int kk = 0; kk < 2; ++kk) {
                const int chunk = ((t * 16 + j) * 2 + kk) * 64 + el;
                Bhi[t][kk] = ((const bf16x8*)wsh)[chunk];
                Blo[t][kk] = ((const bf16x8*)wsl)[chunk];
            }
        #pragma unroll
        for (int s = 0; s < 4; ++s) {
            const int mt  = (p + s) & 3;            // runtime: addresses only
            const int row = mt * 16 + r16;
            const int ch0 = grp ^ (r16 & 7);
            const int ch1 = (4 + grp) ^ (r16 & 7);
            bf16x8 Ah0 = *(const bf16x8*)(smem +        row * 128 + ch0 * 16);
            bf16x8 Ah1 = *(const bf16x8*)(smem +        row * 128 + ch1 * 16);
            bf16x8 Al0 = *(const bf16x8*)(smem + 8192 + row * 128 + ch0 * 16);
            bf16x8 Al1 = *(const bf16x8*)(smem + 8192 + row * 128 + ch1 * 16);
            float4 tv = tv4[j * 16 + mt * 4 + grp];
            #pragma unroll
            for (int t = 0; t < 3; ++t) {
                f32x4 rw = (f32x4){0.f, 0.f, 0.f, 0.f};
                rw = __builtin_amdgcn_mfma_f32_16x16x32_bf16(Ah0, Bhi[t][0], rw, 0, 0, 0);
                rw = __builtin_amdgcn_mfma_f32_16x16x32_bf16(Ah1, Bhi[t][1], rw, 0, 0, 0);
                rw = __builtin_amdgcn_mfma_f32_16x16x32_bf16(Al0, Bhi[t][0], rw, 0, 0, 0);
                rw = __builtin_amdgcn_mfma_f32_16x16x32_bf16(Al1, Bhi[t][1], rw, 0, 0, 0);
                rw = __builtin_amdgcn_mfma_f32_16x16x32_bf16(Ah0, Blo[t][0], rw, 0, 0, 0);
                rw = __builtin_amdgcn_mfma_f32_16x16x32_bf16(Ah1, Blo[t][1], rw, 0, 0, 0);
                acc[s][t].x = fmaf(tv.x, rw.x, acc[s][t].x);
                acc[s][t].y = fmaf(tv.y, rw.y, acc[s][t].y);
                acc[s][t].z = fmaf(tv.z, rw.z, acc[s][t].z);
                acc[s][t].w = fmaf(tv.w, rw.w, acc[s][t].w);
            }
        }
    }

    __syncthreads();   // all h/tv reads done before tmp2 overlays h

    // ===== cross-wave reduction: 4 hand-written rounds, acc index literal =====
    {
        float* t2p = (float*)smem;
        {   // round 0: store slot 0 -> tile p
            const int eb = p * 16 + grp * 4;
            RED_STORE(0);
        }
        __syncthreads();
        {   // round 1: add slot 1 -> tile (p+1)&3
            const int eb = (((p + 1) & 3) * 16) + grp * 4;
            RED_ADD(1);
        }
        __syncthreads();
        {   // round 2: add slot 2 -> tile (p+2)&3
            const int eb = (((p + 2) & 3) * 16) + grp * 4;
            RED_ADD(2);
        }
        __syncthreads();
        {   // round 3: add slot 3 -> tile (p+3)&3
            const int eb = (((p + 3) & 3) * 16) + grp * 4;
            RED_ADD(3);
        }
        __syncthreads();
    }

    // ================= phase C : wave p, lanes 0..15 -> node e0/16 + p =================
    if (el < 16) {
        const int erow = p * 16 + el;          // edge within block
        const int ec   = e0 + erow;            // global edge
        float t2[48];
        {
            const float* t2r = (const float*)smem + (size_t)erow * T2S;
            #pragma unroll
            for (int o2 = 0; o2 < 48; ++o2) t2[o2] = t2r[o2];
        }
        float b2r[8];
        {
            const float4* b24 = reinterpret_cast<const float4*>(b2 + (size_t)ec * 8);
            float4 u0 = b24[0], u1 = b24[1];
            b2r[0]=u0.x; b2r[1]=u0.y; b2r[2]=u0.z; b2r[3]=u0.w;
            b2r[4]=u1.x; b2r[5]=u1.y; b2r[6]=u1.z; b2r[7]=u1.w;
        }
        float q[8][4];
        #pragma unroll
        for (int o = 0; o < 8; ++o) {
            float t0 = t2[2*o+0], t1 = t2[2*o+1];
            #pragma unroll
            for (int d = 0; d < 4; ++d)
                q[o][d] = fmaf(t0, b2r[d], t1 * b2r[4+d]);
        }
        float scores[4] = {0.f, 0.f, 0.f, 0.f};
        #pragma unroll
        for (int o = 0; o < 8; ++o) {
            float t0 = t2[16+2*o+0], t1 = t2[16+2*o+1];
            float sacc = 0.f;
            #pragma unroll
            for (int d = 0; d < 4; ++d) {
                float kr = fmaf(t0, b2r[d], t1 * b2r[4+d]);
                sacc = fmaf(q[o][d], kr, sacc);
            }
            scores[o >> 1] += sacc;
        }
        float vv[8][4];
        #pragma unroll
        for (int o = 0; o < 8; ++o) {
            float t0 = t2[32+2*o+0], t1 = t2[32+2*o+1];
            #pragma unroll
            for (int d = 0; d < 4; ++d)
                vv[o][d] = fmaf(t0, b2r[d], t1 * b2r[4+d]);
        }
        // softmax over the 16 neighbor lanes
        float attn[4];
        #pragma unroll
        for (int hh = 0; hh < 4; ++hh) {
            float s = scores[hh] * 0.35355339059327373f;
            float mx = s;
            #pragma unroll
            for (int msk = 8; msk; msk >>= 1)
                mx = fmaxf(mx, __shfl_xor(mx, msk, 16));
            float pr = __expf(s - mx);
            float ps = pr;
            #pragma unroll
            for (int msk = 8; msk; msk >>= 1)
                ps += __shfl_xor(ps, msk, 16);
            attn[hh] = pr / ps;
        }
        float osum[8][4];
        #pragma unroll
        for (int m = 0; m < 8; ++m) {
            float w = attn[m >> 1];
            #pragma unroll
            for (int d = 0; d < 4; ++d) {
                float val = w * vv[m][d];
                #pragma unroll
                for (int msk = 8; msk; msk >>= 1)
                    val += __shfl_xor(val, msk, 16);
                osum[m][d] = val;
            }
        }
        if (el == 0) {
            const int n = ec >> 4;
            #pragma unroll
            for (int od = 0; od < 8; ++od) {
                #pragma unroll
                for (int d = 0; d < 4; ++d) {
                    const int row = (d == 0) ? od : (8 + od);
                    float a = (d == 0) ? bias[od] : 0.f;
                    #pragma unroll
                    for (int m = 0; m < 8; ++m)
                        a = fmaf(Wout[row * 8 + m], osum[m][d], a);
                    out[(size_t)n * 32 + od * 4 + d] = a;
                }
            }
        }
    }
}

extern "C" void kernel_launch(void* const* d_in, const int* in_sizes, int n_in,
                              void* d_out, int out_size, void* d_ws, size_t ws_size,
                              hipStream_t stream) {
    const float* b1   = (const float*)d_in[0];
    const float* b2   = (const float*)d_in[1];
    const float* ef   = (const float*)d_in[2];
    const float* f    = (const float*)d_in[3];
    const int*   nidx = (const int*)d_in[4];
    const float* W1   = (const float*)d_in[5];
    const float* b1l  = (const float*)d_in[6];
    const float* W2   = (const float*)d_in[7];
    const float* b2l  = (const float*)d_in[8];
    const float* Wout = (const float*)d_in[9];
    const float* bias = (const float*)d_in[10];
    float* out = (float*)d_out;

    uint4* wsh = (uint4*)d_ws;              // 6144 chunks
    uint4* wsl = wsh + 6144;                // 6144 chunks
    uint4* bb  = wsh + 12288;               // 192 chunks

    hipLaunchKernelGGL(w_split, dim3(25), dim3(256), 0, stream, W2, b2l, wsh, wsl, bb);
    hipLaunchKernelGGL(eq_attn_kernel, dim3(NBLK), dim3(TPB), 0, stream,
                       b1, b2, ef, f, nidx, W1, b1l, Wout, bias,
                       (const uint4*)wsh, (const uint4*)wsl, (const uint4*)bb, out);
}